// Round 5
// baseline (114.904 us; speedup 1.0000x reference)
//
#include <hip/hip_runtime.h>
#include <math.h>

// Problem constants (fixed by setup_inputs): B=128, P=4096, L=128
#define BB 128
#define PP 4096
#define LL 128
#define BLOCK 256
#define PROPS 2                         // empirical best (R0/R4 104.2 vs R2 108.5 / R3 107.6)
#define CHUNKS (PP / (BLOCK * PROPS))   // 8 -> 1024 blocks, 4 blocks/CU, 16 waves/CU
#define SCALE 32.0f
#define LCHUNK 8

// v_readlane_b32: broadcast lane 'lane' of v to an SGPR (uniform). VALU op,
// NO LDS pipe involvement — this is the whole point of this revision.
__device__ __forceinline__ float rdlane(float v, int lane) {
    return __uint_as_float((unsigned)__builtin_amdgcn_readlane((int)__float_as_uint(v), lane));
}

__global__ __launch_bounds__(BLOCK) void classifier_loss_kernel(
    const float* __restrict__ cls,     // [B, 2P]
    const float* __restrict__ bbox,    // [B, 4P]
    const float* __restrict__ roi,     // [B, P, 4]
    const float* __restrict__ labels,  // [B, L, 4] raw
    const int* __restrict__ neg_enabled,
    float* __restrict__ out)
{
    // R0-R4 evidence: kernel stuck at ~37.5us with VALU-busy only ~13us,
    // invariant to issue-slot count (R4) and wave count (R2/R3). The shared
    // resource every config saturates is the LDS pipe servicing per-label
    // broadcast ds_read_b128/b32 (64-lane x 16B register fanout each).
    // This version has ZERO DS ops in the hot loop: labels live in per-lane
    // VGPRs (lane l holds labels l and 64+l) and are broadcast per label
    // with v_readlane_b32 (VALU->SGPR, uniform lane index; each consumer
    // VALU op reads <=1 SGPR, which is legal).
    __shared__ float s_red[BLOCK / 64];

    const int b     = blockIdx.x >> 3;            // / CHUNKS (CHUNKS=8)
    const int chunk = blockIdx.x & (CHUNKS - 1);
    const int pbase = chunk * (BLOCK * PROPS) + threadIdx.x;
    const int lane  = threadIdx.x & 63;

    // Per-lane label registers: set s holds label s*64 + lane.
    // x2=x+w, y2=y+h, S=w*h — identical arithmetic to the PASSING R3/R4
    // staging (s_lab4/s_area), so the quantized argmax keys are bit-identical.
    float Lx[2], Ly[2], Lx2[2], Ly2[2], LS[2];
    #pragma unroll
    for (int s = 0; s < 2; ++s) {
        const float4 l4 = *reinterpret_cast<const float4*>(
            labels + ((size_t)b * LL + s * 64 + lane) * 4);
        Lx[s]  = l4.x;
        Ly[s]  = l4.y;
        Lx2[s] = l4.x + l4.z;
        Ly2[s] = l4.y + l4.w;
        LS[s]  = l4.z * l4.w;
    }

    // Per-proposal state (VMEM prefetched; latency hides under IoU loop)
    float rx[PROPS], ry[PROPS], rx2[PROPS], ry2[PROPS], rarea[PROPS];
    float cs0[PROPS], cs1[PROPS];
    float best[PROPS];                 // packed key: c with (127-li) in low 7 bits

    #pragma unroll
    for (int j = 0; j < PROPS; ++j) {
        const int p = pbase + j * BLOCK;
        const float4 r4 = *reinterpret_cast<const float4*>(roi + ((size_t)b * PP + p) * 4);
        cs0[j] = cls[(size_t)b * 2 * PP + p];
        cs1[j] = cls[(size_t)b * 2 * PP + PP + p];
        rx[j]  = r4.x * SCALE;
        ry[j]  = r4.y * SCALE;
        float rw = r4.z * SCALE, rh = r4.w * SCALE;
        rx2[j] = rx[j] + rw;
        ry2[j] = ry[j] + rh;
        rarea[j] = rw * rh;
        best[j] = 0.0f;                // all-miss -> stays 0 -> pos=false
    }
    // NOTE: no __syncthreads needed — no shared staging anymore.

    // --- argmax IoU via packed-key fmax (R0/R3-proven form) ---
    // c = inter/(S+R) = iou/(1+iou) is monotone in iou -> same argmax.
    // key = c with low 7 mantissa bits replaced by (127-li): among quantized-
    // equal c the EARLIER index wins -> matches jnp.argmax tie semantics.
    // rcp rides the transcendental pipe (co-issues with VALU).
    // Two set-loops keep the label-register selection compile-time static
    // (runtime-indexed register arrays would spill to scratch).
    #pragma unroll
    for (int s = 0; s < 2; ++s) {
        const float LxR = Lx[s], LyR = Ly[s], Lx2R = Lx2[s], Ly2R = Ly2[s], LSR = LS[s];
        const int base = s * 64;
        for (int lc = 0; lc < 64; lc += LCHUNK) {
            #pragma unroll
            for (int u = 0; u < LCHUNK; ++u) {
                const int ln = lc + u;               // uniform (SGPR) lane idx
                const int li = base + ln;
                const float lxx = rdlane(LxR,  ln);  // 5x v_readlane per label
                const float lyy = rdlane(LyR,  ln);
                const float lx2 = rdlane(Lx2R, ln);
                const float ly2 = rdlane(Ly2R, ln);
                const float S   = rdlane(LSR,  ln);
                #pragma unroll
                for (int j = 0; j < PROPS; ++j) {
                    float ix = fmaxf(0.0f, fminf(lx2, rx2[j]) - fmaxf(lxx, rx[j]));
                    float iy = fminf(ly2, ry2[j]) - fmaxf(lyy, ry[j]);  // unclamped
                    float inter = ix * iy;           // iy<0 -> inter<=0 -> loses
                    float den = S + rarea[j];
                    float c = inter * __builtin_amdgcn_rcpf(den);
                    unsigned kb = (__float_as_uint(c) & 0xFFFFFF80u) | (unsigned)(127 - li);
                    best[j] = fmaxf(best[j], __uint_as_float(kb));   // single-op update
                }
            }
        }
    }

    const float LOG01 = -2.3025850929940457f;  // log(0.1)
    const float LOG09 = -0.10536051565782628f; // log(0.9)
    const bool neg_on = neg_enabled[0] > 0;

    float acc = 0.0f;
    #pragma unroll
    for (int j = 0; j < PROPS; ++j) {
        const int p = pbase + j * BLOCK;
        const int bidx = 127 - (int)(__float_as_uint(best[j]) & 127u);
        // best > 1e-25: genuine c >= ~1e-14; index-only denormal keys ~1e-43.
        const bool pos = (best[j] > 1e-25f) && (bidx > 0);

        const float mx = fmaxf(cs0[j], cs1[j]);
        const float e0 = expf(cs0[j] - mx);
        const float e1 = expf(cs1[j] - mx);
        const float inv = 1.0f / (e0 + e1);
        const float p0 = e0 * inv, p1 = e1 * inv;
        const float ce_pos = -(p0 * LOG01 + p1 * LOG09);
        const float ce_neg = -(p0 * LOG09 + p1 * LOG01);

        float per;
        if (pos) {
            // Divergent per-lane gather from raw labels (bit-exact x,y,w,h)
            const float* mp = labels + ((size_t)b * LL + bidx) * 4;
            float mxl = mp[0], myl = mp[1], mwl = mp[2], mhl = mp[3];
            float rw = rx2[j] - rx[j];
            float rh = ry2[j] - ry[j];
            float tx = (mxl - rx[j]) / rw;
            float ty = (myl - ry[j]) / rh;
            float tw = logf(fmaxf(mwl / rw, 1e-8f));
            float th = logf(fmaxf(mhl / rh, 1e-8f));
            const float* bp = bbox + (size_t)b * 4 * PP + p;
            float ex = tx - bp[0];
            float ey = ty - bp[PP];
            float ew = tw - bp[2 * PP];
            float eh = th - bp[3 * PP];
            float ax = fabsf(ex), ay = fabsf(ey), aw = fabsf(ew), ah = fabsf(eh);
            float hx = (ax <= 1.0f) ? 0.5f * ex * ex : ax - 0.5f;
            float hy = (ay <= 1.0f) ? 0.5f * ey * ey : ay - 0.5f;
            float hw = (aw <= 1.0f) ? 0.5f * ew * ew : aw - 0.5f;
            float hh = (ah <= 1.0f) ? 0.5f * eh * eh : ah - 0.5f;
            float huber = 0.25f * (hx + hy + hw + hh);
            per = 2.0f * huber + ce_pos;
        } else {
            per = neg_on ? ce_neg : 0.0f;
        }
        acc += per;
    }

    // --- reduce: wave64 shuffle -> LDS -> one atomic per block ---
    float v = acc;
    #pragma unroll
    for (int off = 32; off > 0; off >>= 1)
        v += __shfl_down(v, off, 64);
    if ((threadIdx.x & 63) == 0)
        s_red[threadIdx.x >> 6] = v;
    __syncthreads();
    if (threadIdx.x == 0) {
        float blk = s_red[0] + s_red[1] + s_red[2] + s_red[3];
        atomicAdd(out, blk);
    }
}

extern "C" void kernel_launch(void* const* d_in, const int* in_sizes, int n_in,
                              void* d_out, int out_size, void* d_ws, size_t ws_size,
                              hipStream_t stream) {
    const float* cls    = (const float*)d_in[0];
    const float* bbox   = (const float*)d_in[1];
    const float* roi    = (const float*)d_in[2];
    const float* labels = (const float*)d_in[3];
    const int*   neg    = (const int*)d_in[4];
    float* out = (float*)d_out;

    // Output is a scalar; zero only the accumulator. (The 256 MiB
    // fillBufferAligned dispatches in the profile are HARNESS-side re-poison
    // — not ours, not removable; they set a ~42us + ~25us fixed floor/iter.)
    hipMemsetAsync(out, 0, sizeof(float), stream);
    classifier_loss_kernel<<<dim3(BB * PP / (BLOCK * PROPS)), dim3(BLOCK), 0, stream>>>(
        cls, bbox, roi, labels, neg, out);
}

// Round 6
// 107.456 us; speedup vs baseline: 1.0693x; 1.0693x over previous
//
#include <hip/hip_runtime.h>
#include <math.h>

// Problem constants (fixed by setup_inputs): B=128, P=4096, L=128
#define BB 128
#define PP 4096
#define LL 128
#define BLOCK 256
#define PROPS 2                         // empirical best (R0/R4 104.2 vs R2 108.5 / R3 107.6 / R5 114.9)
#define CHUNKS (PP / (BLOCK * PROPS))   // 8 -> 1024 blocks, 4 blocks/CU, 16 waves/CU
#define SCALE 32.0f
#define LCHUNK 4                        // labels per pipeline buffer

__global__ __launch_bounds__(BLOCK) void classifier_loss_kernel(
    const float* __restrict__ cls,     // [B, 2P]
    const float* __restrict__ bbox,    // [B, 4P]
    const float* __restrict__ roi,     // [B, P, 4]
    const float* __restrict__ labels,  // [B, L, 4] raw
    const int* __restrict__ neg_enabled,
    float* __restrict__ out)
{
    // R0-R5 evidence: ~25us of the ~37.5us kernel is non-issue time,
    // invariant to wave count (R2/R3) and instruction mix (R4/R5). Theory:
    // waves alternate {ds_read batch -> lgkm wait -> VALU burst} in near-
    // lockstep, so SIMDs idle when all 4 resident waves sit in the LDS-wait
    // window together. Fix: REGISTER DOUBLE-BUFFER the label chunks —
    // prefetch chunk k+1 into registers while computing chunk k, so the LDS
    // return latency hides under the previous chunk's ~460-cycle VALU burst.
    // Buffers use only static (unrolled) indexing — runtime-indexed register
    // arrays would spill to scratch.
    __shared__ float4 s_lab4[LL];      // (x, y, x2, y2)
    __shared__ float  s_red[BLOCK / 64];

    const int b     = blockIdx.x >> 3;            // / CHUNKS (CHUNKS=8)
    const int chunk = blockIdx.x & (CHUNKS - 1);
    const int pbase = chunk * (BLOCK * PROPS) + threadIdx.x;

    if (threadIdx.x < LL) {
        const float* lp = labels + ((size_t)b * LL + threadIdx.x) * 4;
        float x = lp[0], y = lp[1], w = lp[2], h = lp[3];
        s_lab4[threadIdx.x] = make_float4(x, y, x + w, y + h);
    }

    // Per-proposal state (VMEM prefetched; latency hides under IoU loop)
    float rx[PROPS], ry[PROPS], rx2[PROPS], ry2[PROPS], rarea[PROPS];
    float cs0[PROPS], cs1[PROPS];
    float best[PROPS];                 // packed key: c with (127-li) in low 7 bits

    #pragma unroll
    for (int j = 0; j < PROPS; ++j) {
        const int p = pbase + j * BLOCK;
        const float4 r4 = *reinterpret_cast<const float4*>(roi + ((size_t)b * PP + p) * 4);
        cs0[j] = cls[(size_t)b * 2 * PP + p];
        cs1[j] = cls[(size_t)b * 2 * PP + PP + p];
        rx[j]  = r4.x * SCALE;
        ry[j]  = r4.y * SCALE;
        float rw = r4.z * SCALE, rh = r4.w * SCALE;
        rx2[j] = rx[j] + rw;
        ry2[j] = ry[j] + rh;
        rarea[j] = rw * rh;
        best[j] = 0.0f;                // all-miss -> stays 0 -> pos=false
    }

    __syncthreads();

    // --- argmax IoU via packed-key fmax (R0-proven arithmetic, bit-identical) ---
    // c = inter/(S+R) = iou/(1+iou) is monotone in iou -> same argmax.
    // key = c with low 7 mantissa bits replaced by (127-li): among quantized-
    // equal c the EARLIER index wins -> matches jnp.argmax tie semantics.
    // rcp rides the transcendental pipe (co-issues with VALU).
    auto process = [&](const float4& l4, int li) {
        const float S = (l4.z - l4.x) * (l4.w - l4.y);   // label area (R0 form)
        #pragma unroll
        for (int j = 0; j < PROPS; ++j) {
            float ix = fmaxf(0.0f, fminf(l4.z, rx2[j]) - fmaxf(l4.x, rx[j]));
            float iy = fminf(l4.w, ry2[j]) - fmaxf(l4.y, ry[j]);  // unclamped
            float inter = ix * iy;               // iy<0 -> inter<=0 -> loses
            float den = S + rarea[j];
            float c = inter * __builtin_amdgcn_rcpf(den);
            unsigned kb = (__float_as_uint(c) & 0xFFFFFF80u) | (unsigned)(127 - li);
            best[j] = fmaxf(best[j], __uint_as_float(kb));   // single-op update
        }
    };

    // Software pipeline: two LCHUNK-deep register buffers, alternating.
    // ds_reads for the NEXT chunk are issued before the CURRENT chunk's
    // compute, so lgkm latency overlaps VALU.
    float4 A[LCHUNK], Bv[LCHUNK];
    #pragma unroll
    for (int u = 0; u < LCHUNK; ++u) A[u] = s_lab4[u];

    for (int k = 0; k < LL / (2 * LCHUNK); ++k) {      // 16 iterations
        const int base = k * 2 * LCHUNK;
        #pragma unroll
        for (int u = 0; u < LCHUNK; ++u) Bv[u] = s_lab4[base + LCHUNK + u];
        #pragma unroll
        for (int u = 0; u < LCHUNK; ++u) process(A[u], base + u);
        const int nb = (base + 2 * LCHUNK) & (LL - 1); // wraps to 0 on last iter (harmless)
        #pragma unroll
        for (int u = 0; u < LCHUNK; ++u) A[u] = s_lab4[nb + u];
        #pragma unroll
        for (int u = 0; u < LCHUNK; ++u) process(Bv[u], base + LCHUNK + u);
    }

    const float LOG01 = -2.3025850929940457f;  // log(0.1)
    const float LOG09 = -0.10536051565782628f; // log(0.9)
    const bool neg_on = neg_enabled[0] > 0;

    float acc = 0.0f;
    #pragma unroll
    for (int j = 0; j < PROPS; ++j) {
        const int p = pbase + j * BLOCK;
        const int bidx = 127 - (int)(__float_as_uint(best[j]) & 127u);
        // best > 1e-25: genuine c >= ~1e-14; index-only denormal keys ~1e-43.
        const bool pos = (best[j] > 1e-25f) && (bidx > 0);

        const float mx = fmaxf(cs0[j], cs1[j]);
        const float e0 = expf(cs0[j] - mx);
        const float e1 = expf(cs1[j] - mx);
        const float inv = 1.0f / (e0 + e1);
        const float p0 = e0 * inv, p1 = e1 * inv;
        const float ce_pos = -(p0 * LOG01 + p1 * LOG09);
        const float ce_neg = -(p0 * LOG09 + p1 * LOG01);

        float per;
        if (pos) {
            // Divergent per-lane gather from raw labels (bit-exact x,y,w,h)
            const float* mp = labels + ((size_t)b * LL + bidx) * 4;
            float mxl = mp[0], myl = mp[1], mwl = mp[2], mhl = mp[3];
            float rw = rx2[j] - rx[j];
            float rh = ry2[j] - ry[j];
            float tx = (mxl - rx[j]) / rw;
            float ty = (myl - ry[j]) / rh;
            float tw = logf(fmaxf(mwl / rw, 1e-8f));
            float th = logf(fmaxf(mhl / rh, 1e-8f));
            const float* bp = bbox + (size_t)b * 4 * PP + p;
            float ex = tx - bp[0];
            float ey = ty - bp[PP];
            float ew = tw - bp[2 * PP];
            float eh = th - bp[3 * PP];
            float ax = fabsf(ex), ay = fabsf(ey), aw = fabsf(ew), ah = fabsf(eh);
            float hx = (ax <= 1.0f) ? 0.5f * ex * ex : ax - 0.5f;
            float hy = (ay <= 1.0f) ? 0.5f * ey * ey : ay - 0.5f;
            float hw = (aw <= 1.0f) ? 0.5f * ew * ew : aw - 0.5f;
            float hh = (ah <= 1.0f) ? 0.5f * eh * eh : ah - 0.5f;
            float huber = 0.25f * (hx + hy + hw + hh);
            per = 2.0f * huber + ce_pos;
        } else {
            per = neg_on ? ce_neg : 0.0f;
        }
        acc += per;
    }

    // --- reduce: wave64 shuffle -> LDS -> one atomic per block ---
    float v = acc;
    #pragma unroll
    for (int off = 32; off > 0; off >>= 1)
        v += __shfl_down(v, off, 64);
    if ((threadIdx.x & 63) == 0)
        s_red[threadIdx.x >> 6] = v;
    __syncthreads();
    if (threadIdx.x == 0) {
        float blk = s_red[0] + s_red[1] + s_red[2] + s_red[3];
        atomicAdd(out, blk);
    }
}

extern "C" void kernel_launch(void* const* d_in, const int* in_sizes, int n_in,
                              void* d_out, int out_size, void* d_ws, size_t ws_size,
                              hipStream_t stream) {
    const float* cls    = (const float*)d_in[0];
    const float* bbox   = (const float*)d_in[1];
    const float* roi    = (const float*)d_in[2];
    const float* labels = (const float*)d_in[3];
    const int*   neg    = (const int*)d_in[4];
    float* out = (float*)d_out;

    // Output is a scalar; zero only the accumulator. (The 256 MiB
    // fillBufferAligned dispatches in the profile are HARNESS-side re-poison
    // — not ours, not removable; fixed per-iteration overhead ≈ 66.7 us,
    // kernel time adds 1:1 on top.)
    hipMemsetAsync(out, 0, sizeof(float), stream);
    classifier_loss_kernel<<<dim3(BB * PP / (BLOCK * PROPS)), dim3(BLOCK), 0, stream>>>(
        cls, bbox, roi, labels, neg, out);
}